// Round 1
// baseline (814.980 us; speedup 1.0000x reference)
//
#include <hip/hip_runtime.h>
#include <hip/hip_bf16.h>

// Problem constants (match reference)
#define NN 100000
#define EE 1600000
#define INF_DIM 128
#define NHEAD 4
#define HDIM 32
#define NEG_SLOPE 0.2f

// ---------------------------------------------------------------------------
// GEMM: C[M,128] = A[M,128] @ W[128,128]^T (+bias), W row-major [o][k]
// Tiled fp32: BM=64, BN=128, BK=32; 256 threads; per-thread 8x4 micro-tile.
// ---------------------------------------------------------------------------
__global__ __launch_bounds__(256) void gemm128(const float* __restrict__ A,
                                               const float* __restrict__ W,
                                               const float* __restrict__ bias,
                                               float* __restrict__ C, int M) {
  __shared__ float sA[32][64 + 4];   // [k][m], pad 4 keeps float4 alignment
  __shared__ float sW[32][128 + 4];  // [k][o]
  const int tid = threadIdx.x;
  const int m0 = blockIdx.x * 64;
  const int tx = tid & 31;  // col group: o = tx*4 .. tx*4+3
  const int ty = tid >> 5;  // row group: m = ty*8 .. ty*8+7
  const int fr = tid & 7;   // float4 column within K-chunk
  const int rr = tid >> 3;  // 0..31

  float acc[8][4];
#pragma unroll
  for (int i = 0; i < 8; ++i)
#pragma unroll
    for (int j = 0; j < 4; ++j) acc[i][j] = 0.f;

  for (int kk = 0; kk < 128; kk += 32) {
    // stage A tile (transposed into [k][m])
#pragma unroll
    for (int half = 0; half < 2; ++half) {
      const int row = rr + half * 32;
      const int gm = m0 + row;
      float4 v = make_float4(0.f, 0.f, 0.f, 0.f);
      if (gm < M) v = *(const float4*)&A[(size_t)gm * 128 + kk + fr * 4];
      sA[fr * 4 + 0][row] = v.x;
      sA[fr * 4 + 1][row] = v.y;
      sA[fr * 4 + 2][row] = v.z;
      sA[fr * 4 + 3][row] = v.w;
    }
    // stage W tile (transposed into [k][o])
#pragma unroll
    for (int q = 0; q < 4; ++q) {
      const int o = rr + q * 32;
      const float4 v = *(const float4*)&W[(size_t)o * 128 + kk + fr * 4];
      sW[fr * 4 + 0][o] = v.x;
      sW[fr * 4 + 1][o] = v.y;
      sW[fr * 4 + 2][o] = v.z;
      sW[fr * 4 + 3][o] = v.w;
    }
    __syncthreads();
#pragma unroll
    for (int k = 0; k < 32; ++k) {
      const float4 a0 = *(const float4*)&sA[k][ty * 8];
      const float4 a1 = *(const float4*)&sA[k][ty * 8 + 4];
      const float4 w = *(const float4*)&sW[k][tx * 4];
      const float am[8] = {a0.x, a0.y, a0.z, a0.w, a1.x, a1.y, a1.z, a1.w};
      const float wn[4] = {w.x, w.y, w.z, w.w};
#pragma unroll
      for (int i = 0; i < 8; ++i)
#pragma unroll
        for (int j = 0; j < 4; ++j) acc[i][j] += am[i] * wn[j];
    }
    __syncthreads();
  }
  const int o = tx * 4;
  float4 b = make_float4(0.f, 0.f, 0.f, 0.f);
  if (bias) b = *(const float4*)&bias[o];
#pragma unroll
  for (int i = 0; i < 8; ++i) {
    const int gm = m0 + ty * 8 + i;
    if (gm < M) {
      float4 r;
      r.x = acc[i][0] + b.x;
      r.y = acc[i][1] + b.y;
      r.z = acc[i][2] + b.z;
      r.w = acc[i][3] + b.w;
      *(float4*)&C[(size_t)gm * 128 + o] = r;
    }
  }
}

// ---------------------------------------------------------------------------
// a_s[n,h] = dot(h[n,h,:], att_src[h,:]); a_d likewise. One thread per (n,h).
// ---------------------------------------------------------------------------
__global__ void attn_dots(const float* __restrict__ h,
                          const float* __restrict__ att_src,
                          const float* __restrict__ att_dst,
                          float* __restrict__ a_s, float* __restrict__ a_d) {
  const int idx = blockIdx.x * blockDim.x + threadIdx.x;  // n*4 + head
  if (idx >= NN * NHEAD) return;
  const int hd = idx & 3;
  const float4* hp = (const float4*)(h + (size_t)idx * HDIM);
  const float4* as = (const float4*)(att_src + hd * HDIM);
  const float4* ad = (const float4*)(att_dst + hd * HDIM);
  float s = 0.f, d = 0.f;
#pragma unroll
  for (int j = 0; j < 8; ++j) {
    const float4 v = hp[j], a = as[j], b = ad[j];
    s += v.x * a.x + v.y * a.y + v.z * a.z + v.w * a.w;
    d += v.x * b.x + v.y * b.y + v.z * b.z + v.w * b.w;
  }
  a_s[idx] = s;
  a_d[idx] = d;
}

// ---------------------------------------------------------------------------
// CSR build: histogram of dst, exclusive scan, scatter src ids.
// ---------------------------------------------------------------------------
__global__ void hist_kernel(const int* __restrict__ dst, int* __restrict__ deg) {
  const int i = blockIdx.x * blockDim.x + threadIdx.x;
  if (i < EE) atomicAdd(&deg[dst[i]], 1);
}

__global__ __launch_bounds__(1024) void scan_kernel(const int* __restrict__ deg,
                                                    int* __restrict__ rowptr,
                                                    int* __restrict__ cur) {
  __shared__ int ls[1024];
  const int t = threadIdx.x;
  const int chunk = (NN + 1023) / 1024;
  const int lo = t * chunk;
  const int hi = min(lo + chunk, NN);
  int s = 0;
  for (int i = lo; i < hi; ++i) s += deg[i];
  ls[t] = s;
  __syncthreads();
  for (int off = 1; off < 1024; off <<= 1) {
    const int v = (t >= off) ? ls[t - off] : 0;
    __syncthreads();
    ls[t] += v;
    __syncthreads();
  }
  int run = ls[t] - s;  // exclusive prefix
  for (int i = lo; i < hi; ++i) {
    rowptr[i] = run;
    cur[i] = run;
    run += deg[i];
  }
  if (t == 1023) rowptr[NN] = ls[1023];
}

__global__ void scatter_kernel(const int* __restrict__ src,
                               const int* __restrict__ dst,
                               int* __restrict__ cur, int* __restrict__ col) {
  const int i = blockIdx.x * blockDim.x + threadIdx.x;
  if (i < EE) {
    const int d = dst[i];
    const int p = atomicAdd(&cur[d], 1);
    col[p] = src[i];
  }
}

// ---------------------------------------------------------------------------
// Aggregate: one wave per destination node. Unnormalized exp weights summed
// with features; divide by denom at the end (max-subtraction skipped: cancels
// exactly, logits are O(1)). Self loop handled inline. Output is relu'd.
// ---------------------------------------------------------------------------
__global__ __launch_bounds__(256) void aggregate_kernel(
    const float* __restrict__ h, const float* __restrict__ a_s,
    const float* __restrict__ a_d, const float* __restrict__ bias_gat,
    const int* __restrict__ rowptr, const int* __restrict__ col,
    float* __restrict__ out1) {
  const int wave = (blockIdx.x * blockDim.x + threadIdx.x) >> 6;
  const int lane = threadIdx.x & 63;
  if (wave >= NN) return;
  const int n = wave;
  const int h0 = lane >> 5;      // head for element `lane`
  const int h1 = 2 + h0;         // head for element `64+lane`
  const float ad0 = a_d[n * 4 + h0];
  const float ad1 = a_d[n * 4 + h1];

  float acc0, acc1, ds0, ds1;
  {  // self loop
    float l0 = a_s[n * 4 + h0] + ad0;
    l0 = l0 > 0.f ? l0 : NEG_SLOPE * l0;
    float l1 = a_s[n * 4 + h1] + ad1;
    l1 = l1 > 0.f ? l1 : NEG_SLOPE * l1;
    const float e0 = __expf(l0), e1 = __expf(l1);
    acc0 = e0 * h[(size_t)n * 128 + lane];
    acc1 = e1 * h[(size_t)n * 128 + 64 + lane];
    ds0 = e0;
    ds1 = e1;
  }
  const int beg = rowptr[n];
  const int end = rowptr[n + 1];
  for (int i = beg; i < end; ++i) {
    const int s = col[i];
    float l0 = a_s[s * 4 + h0] + ad0;
    l0 = l0 > 0.f ? l0 : NEG_SLOPE * l0;
    float l1 = a_s[s * 4 + h1] + ad1;
    l1 = l1 > 0.f ? l1 : NEG_SLOPE * l1;
    const float e0 = __expf(l0), e1 = __expf(l1);
    acc0 += e0 * h[(size_t)s * 128 + lane];
    acc1 += e1 * h[(size_t)s * 128 + 64 + lane];
    ds0 += e0;
    ds1 += e1;
  }
  float v0 = acc0 / ds0 + bias_gat[lane];
  float v1 = acc1 / ds1 + bias_gat[64 + lane];
  out1[(size_t)n * 128 + lane] = v0 > 0.f ? v0 : 0.f;
  out1[(size_t)n * 128 + 64 + lane] = v1 > 0.f ? v1 : 0.f;
}

// ---------------------------------------------------------------------------
extern "C" void kernel_launch(void* const* d_in, const int* in_sizes, int n_in,
                              void* d_out, int out_size, void* d_ws,
                              size_t ws_size, hipStream_t stream) {
  const float* x = (const float*)d_in[0];
  const int* ei = (const int*)d_in[1];  // [2,E]: row0=src, row1=dst
  const float* W_gat = (const float*)d_in[2];
  const float* att_src = (const float*)d_in[3];
  const float* att_dst = (const float*)d_in[4];
  const float* bias_gat = (const float*)d_in[5];
  const float* W_lin = (const float*)d_in[6];
  const float* b_lin = (const float*)d_in[7];
  float* out = (float*)d_out;

  // workspace carve-up (all 16B aligned)
  char* ws = (char*)d_ws;
  size_t off = 0;
  float* h = (float*)(ws + off); off += (size_t)NN * 128 * 4;      // 51.2 MB
  float* a_s = (float*)(ws + off); off += (size_t)NN * 4 * 4;      // 1.6 MB
  float* a_d = (float*)(ws + off); off += (size_t)NN * 4 * 4;      // 1.6 MB
  float* out1 = (float*)(ws + off); off += (size_t)NN * 128 * 4;   // 51.2 MB
  int* deg = (int*)(ws + off); off += (size_t)NN * 4;
  int* rowptr = (int*)(ws + off); off += (size_t)(NN + 4) * 4;
  int* cur = (int*)(ws + off); off += (size_t)NN * 4;
  int* col = (int*)(ws + off); off += (size_t)EE * 4;              // 6.4 MB

  const int* src = ei;
  const int* dst = ei + EE;

  // 1) h = x @ W_gat^T
  gemm128<<<(NN + 63) / 64, 256, 0, stream>>>(x, W_gat, nullptr, h, NN);
  // 2) attention dots
  attn_dots<<<(NN * NHEAD + 255) / 256, 256, 0, stream>>>(h, att_src, att_dst,
                                                          a_s, a_d);
  // 3) CSR by destination
  hipMemsetAsync(deg, 0, (size_t)NN * 4, stream);
  hist_kernel<<<(EE + 255) / 256, 256, 0, stream>>>(dst, deg);
  scan_kernel<<<1, 1024, 0, stream>>>(deg, rowptr, cur);
  scatter_kernel<<<(EE + 255) / 256, 256, 0, stream>>>(src, dst, cur, col);
  // 4) softmax-weighted aggregation (+bias, relu) — one wave per node
  aggregate_kernel<<<(NN + 3) / 4, 256, 0, stream>>>(h, a_s, a_d, bias_gat,
                                                     rowptr, col, out1);
  // 5) out = out1 @ W_lin^T + b_lin
  gemm128<<<(NN + 63) / 64, 256, 0, stream>>>(out1, W_lin, b_lin, out, NN);
}

// Round 2
// 611.036 us; speedup vs baseline: 1.3338x; 1.3338x over previous
//
#include <hip/hip_runtime.h>
#include <hip/hip_bf16.h>

// Problem constants (match reference)
#define NN 100000
#define EE 1600000
#define INF_DIM 128
#define NHEAD 4
#define HDIM 32
#define NEG_SLOPE 0.2f

// ---------------------------------------------------------------------------
// GEMM: C[M,128] = A[M,128] @ W[128,128]^T (+bias), W row-major [o][k]
// Tiled fp32: BM=64, BN=128, BK=32; 256 threads; per-thread 8x4 micro-tile.
// ---------------------------------------------------------------------------
__global__ __launch_bounds__(256) void gemm128(const float* __restrict__ A,
                                               const float* __restrict__ W,
                                               const float* __restrict__ bias,
                                               float* __restrict__ C, int M) {
  __shared__ float sA[32][64 + 4];   // [k][m], pad 4 keeps float4 alignment
  __shared__ float sW[32][128 + 4];  // [k][o]
  const int tid = threadIdx.x;
  const int m0 = blockIdx.x * 64;
  const int tx = tid & 31;  // col group: o = tx*4 .. tx*4+3
  const int ty = tid >> 5;  // row group: m = ty*8 .. ty*8+7
  const int fr = tid & 7;   // float4 column within K-chunk
  const int rr = tid >> 3;  // 0..31

  float acc[8][4];
#pragma unroll
  for (int i = 0; i < 8; ++i)
#pragma unroll
    for (int j = 0; j < 4; ++j) acc[i][j] = 0.f;

  for (int kk = 0; kk < 128; kk += 32) {
    // stage A tile (transposed into [k][m])
#pragma unroll
    for (int half = 0; half < 2; ++half) {
      const int row = rr + half * 32;
      const int gm = m0 + row;
      float4 v = make_float4(0.f, 0.f, 0.f, 0.f);
      if (gm < M) v = *(const float4*)&A[(size_t)gm * 128 + kk + fr * 4];
      sA[fr * 4 + 0][row] = v.x;
      sA[fr * 4 + 1][row] = v.y;
      sA[fr * 4 + 2][row] = v.z;
      sA[fr * 4 + 3][row] = v.w;
    }
    // stage W tile (transposed into [k][o])
#pragma unroll
    for (int q = 0; q < 4; ++q) {
      const int o = rr + q * 32;
      const float4 v = *(const float4*)&W[(size_t)o * 128 + kk + fr * 4];
      sW[fr * 4 + 0][o] = v.x;
      sW[fr * 4 + 1][o] = v.y;
      sW[fr * 4 + 2][o] = v.z;
      sW[fr * 4 + 3][o] = v.w;
    }
    __syncthreads();
#pragma unroll
    for (int k = 0; k < 32; ++k) {
      const float4 a0 = *(const float4*)&sA[k][ty * 8];
      const float4 a1 = *(const float4*)&sA[k][ty * 8 + 4];
      const float4 w = *(const float4*)&sW[k][tx * 4];
      const float am[8] = {a0.x, a0.y, a0.z, a0.w, a1.x, a1.y, a1.z, a1.w};
      const float wn[4] = {w.x, w.y, w.z, w.w};
#pragma unroll
      for (int i = 0; i < 8; ++i)
#pragma unroll
        for (int j = 0; j < 4; ++j) acc[i][j] += am[i] * wn[j];
    }
    __syncthreads();
  }
  const int o = tx * 4;
  float4 b = make_float4(0.f, 0.f, 0.f, 0.f);
  if (bias) b = *(const float4*)&bias[o];
#pragma unroll
  for (int i = 0; i < 8; ++i) {
    const int gm = m0 + ty * 8 + i;
    if (gm < M) {
      float4 r;
      r.x = acc[i][0] + b.x;
      r.y = acc[i][1] + b.y;
      r.z = acc[i][2] + b.z;
      r.w = acc[i][3] + b.w;
      *(float4*)&C[(size_t)gm * 128 + o] = r;
    }
  }
}

// ---------------------------------------------------------------------------
// a_s[n,h] = dot(h[n,h,:], att_src[h,:]); a_d likewise. One thread per (n,h).
// ---------------------------------------------------------------------------
__global__ void attn_dots(const float* __restrict__ h,
                          const float* __restrict__ att_src,
                          const float* __restrict__ att_dst,
                          float* __restrict__ a_s, float* __restrict__ a_d) {
  const int idx = blockIdx.x * blockDim.x + threadIdx.x;  // n*4 + head
  if (idx >= NN * NHEAD) return;
  const int hd = idx & 3;
  const float4* hp = (const float4*)(h + (size_t)idx * HDIM);
  const float4* as = (const float4*)(att_src + hd * HDIM);
  const float4* ad = (const float4*)(att_dst + hd * HDIM);
  float s = 0.f, d = 0.f;
#pragma unroll
  for (int j = 0; j < 8; ++j) {
    const float4 v = hp[j], a = as[j], b = ad[j];
    s += v.x * a.x + v.y * a.y + v.z * a.z + v.w * a.w;
    d += v.x * b.x + v.y * b.y + v.z * b.z + v.w * b.w;
  }
  a_s[idx] = s;
  a_d[idx] = d;
}

// ---------------------------------------------------------------------------
// CSR build: histogram of dst, segment allocation via wave-scan + one atomic
// per wave (segment placement order is irrelevant for correctness), scatter.
// ---------------------------------------------------------------------------
__global__ void hist_kernel(const int* __restrict__ dst, int* __restrict__ deg) {
  const int i = blockIdx.x * blockDim.x + threadIdx.x;
  if (i < EE) atomicAdd(&deg[dst[i]], 1);
}

__global__ __launch_bounds__(256) void alloc_kernel(const int* __restrict__ deg,
                                                    int* __restrict__ rowptr,
                                                    int* __restrict__ cur,
                                                    int* __restrict__ counter) {
  const int i = blockIdx.x * blockDim.x + threadIdx.x;
  const int lane = threadIdx.x & 63;
  const int d = (i < NN) ? deg[i] : 0;
  // 64-lane inclusive shuffle scan
  int s = d;
#pragma unroll
  for (int off = 1; off < 64; off <<= 1) {
    const int v = __shfl_up(s, off, 64);
    if (lane >= off) s += v;
  }
  const int total = __shfl(s, 63, 64);
  int base = 0;
  if (lane == 63) base = atomicAdd(counter, total);
  base = __shfl(base, 63, 64);
  const int p = base + s - d;  // exclusive within wave
  if (i < NN) {
    rowptr[i] = p;
    cur[i] = p;
  }
}

__global__ void scatter_kernel(const int* __restrict__ src,
                               const int* __restrict__ dst,
                               int* __restrict__ cur, int* __restrict__ col) {
  const int i = blockIdx.x * blockDim.x + threadIdx.x;
  if (i < EE) {
    const int d = dst[i];
    const int p = atomicAdd(&cur[d], 1);
    col[p] = src[i];
  }
}

// ---------------------------------------------------------------------------
// Aggregate: one wave per destination node. Unnormalized exp weights summed
// with features; divide by denom at the end (max-subtraction skipped: cancels
// exactly, logits are O(1)). Self loop handled inline. Output is relu'd.
// ---------------------------------------------------------------------------
__global__ __launch_bounds__(256) void aggregate_kernel(
    const float* __restrict__ h, const float* __restrict__ a_s,
    const float* __restrict__ a_d, const float* __restrict__ bias_gat,
    const int* __restrict__ rowptr, const int* __restrict__ deg,
    const int* __restrict__ col, float* __restrict__ out1) {
  const int wave = (blockIdx.x * blockDim.x + threadIdx.x) >> 6;
  const int lane = threadIdx.x & 63;
  if (wave >= NN) return;
  const int n = wave;
  const int h0 = lane >> 5;  // head for element `lane`
  const int h1 = 2 + h0;     // head for element `64+lane`
  const float ad0 = a_d[n * 4 + h0];
  const float ad1 = a_d[n * 4 + h1];

  float acc0, acc1, ds0, ds1;
  {  // self loop
    float l0 = a_s[n * 4 + h0] + ad0;
    l0 = l0 > 0.f ? l0 : NEG_SLOPE * l0;
    float l1 = a_s[n * 4 + h1] + ad1;
    l1 = l1 > 0.f ? l1 : NEG_SLOPE * l1;
    const float e0 = __expf(l0), e1 = __expf(l1);
    acc0 = e0 * h[(size_t)n * 128 + lane];
    acc1 = e1 * h[(size_t)n * 128 + 64 + lane];
    ds0 = e0;
    ds1 = e1;
  }
  const int beg = rowptr[n];
  const int end = beg + deg[n];
  for (int i = beg; i < end; ++i) {
    const int s = col[i];
    float l0 = a_s[s * 4 + h0] + ad0;
    l0 = l0 > 0.f ? l0 : NEG_SLOPE * l0;
    float l1 = a_s[s * 4 + h1] + ad1;
    l1 = l1 > 0.f ? l1 : NEG_SLOPE * l1;
    const float e0 = __expf(l0), e1 = __expf(l1);
    acc0 += e0 * h[(size_t)s * 128 + lane];
    acc1 += e1 * h[(size_t)s * 128 + 64 + lane];
    ds0 += e0;
    ds1 += e1;
  }
  float v0 = acc0 / ds0 + bias_gat[lane];
  float v1 = acc1 / ds1 + bias_gat[64 + lane];
  out1[(size_t)n * 128 + lane] = v0 > 0.f ? v0 : 0.f;
  out1[(size_t)n * 128 + 64 + lane] = v1 > 0.f ? v1 : 0.f;
}

// ---------------------------------------------------------------------------
extern "C" void kernel_launch(void* const* d_in, const int* in_sizes, int n_in,
                              void* d_out, int out_size, void* d_ws,
                              size_t ws_size, hipStream_t stream) {
  const float* x = (const float*)d_in[0];
  const int* ei = (const int*)d_in[1];  // [2,E]: row0=src, row1=dst
  const float* W_gat = (const float*)d_in[2];
  const float* att_src = (const float*)d_in[3];
  const float* att_dst = (const float*)d_in[4];
  const float* bias_gat = (const float*)d_in[5];
  const float* W_lin = (const float*)d_in[6];
  const float* b_lin = (const float*)d_in[7];
  float* out = (float*)d_out;

  // workspace carve-up (all 16B aligned)
  char* ws = (char*)d_ws;
  size_t off = 0;
  float* h = (float*)(ws + off); off += (size_t)NN * 128 * 4;      // 51.2 MB
  float* a_s = (float*)(ws + off); off += (size_t)NN * 4 * 4;      // 1.6 MB
  float* a_d = (float*)(ws + off); off += (size_t)NN * 4 * 4;      // 1.6 MB
  float* out1 = (float*)(ws + off); off += (size_t)NN * 128 * 4;   // 51.2 MB
  int* deg = (int*)(ws + off); off += (size_t)NN * 4;
  int* rowptr = (int*)(ws + off); off += (size_t)(NN + 4) * 4;
  int* cur = (int*)(ws + off); off += (size_t)NN * 4;
  int* counter = (int*)(ws + off); off += 16;
  int* col = (int*)(ws + off); off += (size_t)EE * 4;              // 6.4 MB

  const int* src = ei;
  const int* dst = ei + EE;

  // 1) h = x @ W_gat^T
  gemm128<<<(NN + 63) / 64, 256, 0, stream>>>(x, W_gat, nullptr, h, NN);
  // 2) attention dots
  attn_dots<<<(NN * NHEAD + 255) / 256, 256, 0, stream>>>(h, att_src, att_dst,
                                                          a_s, a_d);
  // 3) CSR by destination (deg histogram, atomic segment alloc, scatter)
  hipMemsetAsync(deg, 0, (size_t)NN * 4, stream);
  hipMemsetAsync(counter, 0, 16, stream);
  hist_kernel<<<(EE + 255) / 256, 256, 0, stream>>>(dst, deg);
  alloc_kernel<<<(NN + 255) / 256, 256, 0, stream>>>(deg, rowptr, cur, counter);
  scatter_kernel<<<(EE + 255) / 256, 256, 0, stream>>>(src, dst, cur, col);
  // 4) softmax-weighted aggregation (+bias, relu) — one wave per node
  aggregate_kernel<<<(NN + 3) / 4, 256, 0, stream>>>(h, a_s, a_d, bias_gat,
                                                     rowptr, deg, col, out1);
  // 5) out = out1 @ W_lin^T + b_lin
  gemm128<<<(NN + 63) / 64, 256, 0, stream>>>(out1, W_lin, b_lin, out, NN);
}

// Round 3
// 549.244 us; speedup vs baseline: 1.4838x; 1.1125x over previous
//
#include <hip/hip_runtime.h>
#include <hip/hip_bf16.h>

// Problem constants (match reference)
#define NN 100000
#define EE 1600000
#define INF_DIM 128
#define NHEAD 4
#define HDIM 32
#define NEG_SLOPE 0.2f

__device__ __forceinline__ unsigned short f2bf(float x) {
  union { float f; unsigned int u; } c;
  c.f = x;
  const unsigned int r = c.u + 0x7fffu + ((c.u >> 16) & 1u);  // RNE
  return (unsigned short)(r >> 16);
}
__device__ __forceinline__ float bf2f(unsigned short u) {
  union { unsigned int u; float f; } c;
  c.u = ((unsigned int)u) << 16;
  return c.f;
}

// ---------------------------------------------------------------------------
// GEMM: C[M,128] = A[M,128] @ W[128,128]^T (+bias), W row-major [o][k]
// Tiled fp32: BM=64, BN=128, BK=32; 256 threads; per-thread 8x4 micro-tile.
// ---------------------------------------------------------------------------
__global__ __launch_bounds__(256) void gemm128(const float* __restrict__ A,
                                               const float* __restrict__ W,
                                               const float* __restrict__ bias,
                                               float* __restrict__ C, int M) {
  __shared__ float sA[32][64 + 4];   // [k][m]
  __shared__ float sW[32][128 + 4];  // [k][o]
  const int tid = threadIdx.x;
  const int m0 = blockIdx.x * 64;
  const int tx = tid & 31;
  const int ty = tid >> 5;
  const int fr = tid & 7;
  const int rr = tid >> 3;

  float acc[8][4];
#pragma unroll
  for (int i = 0; i < 8; ++i)
#pragma unroll
    for (int j = 0; j < 4; ++j) acc[i][j] = 0.f;

  for (int kk = 0; kk < 128; kk += 32) {
#pragma unroll
    for (int half = 0; half < 2; ++half) {
      const int row = rr + half * 32;
      const int gm = m0 + row;
      float4 v = make_float4(0.f, 0.f, 0.f, 0.f);
      if (gm < M) v = *(const float4*)&A[(size_t)gm * 128 + kk + fr * 4];
      sA[fr * 4 + 0][row] = v.x;
      sA[fr * 4 + 1][row] = v.y;
      sA[fr * 4 + 2][row] = v.z;
      sA[fr * 4 + 3][row] = v.w;
    }
#pragma unroll
    for (int q = 0; q < 4; ++q) {
      const int o = rr + q * 32;
      const float4 v = *(const float4*)&W[(size_t)o * 128 + kk + fr * 4];
      sW[fr * 4 + 0][o] = v.x;
      sW[fr * 4 + 1][o] = v.y;
      sW[fr * 4 + 2][o] = v.z;
      sW[fr * 4 + 3][o] = v.w;
    }
    __syncthreads();
#pragma unroll
    for (int k = 0; k < 32; ++k) {
      const float4 a0 = *(const float4*)&sA[k][ty * 8];
      const float4 a1 = *(const float4*)&sA[k][ty * 8 + 4];
      const float4 w = *(const float4*)&sW[k][tx * 4];
      const float am[8] = {a0.x, a0.y, a0.z, a0.w, a1.x, a1.y, a1.z, a1.w};
      const float wn[4] = {w.x, w.y, w.z, w.w};
#pragma unroll
      for (int i = 0; i < 8; ++i)
#pragma unroll
        for (int j = 0; j < 4; ++j) acc[i][j] += am[i] * wn[j];
    }
    __syncthreads();
  }
  const int o = tx * 4;
  float4 b = make_float4(0.f, 0.f, 0.f, 0.f);
  if (bias) b = *(const float4*)&bias[o];
#pragma unroll
  for (int i = 0; i < 8; ++i) {
    const int gm = m0 + ty * 8 + i;
    if (gm < M) {
      float4 r;
      r.x = acc[i][0] + b.x;
      r.y = acc[i][1] + b.y;
      r.z = acc[i][2] + b.z;
      r.w = acc[i][3] + b.w;
      *(float4*)&C[(size_t)gm * 128 + o] = r;
    }
  }
}

// ---------------------------------------------------------------------------
// a_s[n,h] = dot(h[n,h,:], att_src[h,:]); a_d likewise. One thread per (n,h).
// Also emits hb = bf16 copy of h (gather source for aggregate).
// ---------------------------------------------------------------------------
__global__ void attn_dots(const float* __restrict__ h,
                          const float* __restrict__ att_src,
                          const float* __restrict__ att_dst,
                          float* __restrict__ a_s, float* __restrict__ a_d,
                          unsigned short* __restrict__ hb) {
  const int idx = blockIdx.x * blockDim.x + threadIdx.x;  // n*4 + head
  if (idx >= NN * NHEAD) return;
  const int hd = idx & 3;
  const float4* hp = (const float4*)(h + (size_t)idx * HDIM);
  const float4* as = (const float4*)(att_src + hd * HDIM);
  const float4* ad = (const float4*)(att_dst + hd * HDIM);
  float s = 0.f, d = 0.f;
#pragma unroll
  for (int j = 0; j < 8; ++j) {
    const float4 v = hp[j], a = as[j], b = ad[j];
    s += v.x * a.x + v.y * a.y + v.z * a.z + v.w * a.w;
    d += v.x * b.x + v.y * b.y + v.z * b.z + v.w * b.w;
    ushort4 u;
    u.x = f2bf(v.x);
    u.y = f2bf(v.y);
    u.z = f2bf(v.z);
    u.w = f2bf(v.w);
    *(ushort4*)(hb + (size_t)idx * HDIM + j * 4) = u;
  }
  a_s[idx] = s;
  a_d[idx] = d;
}

// ---------------------------------------------------------------------------
// CSR build: histogram of dst, segment allocation via wave-scan + one atomic
// per wave, scatter (fused with per-edge softmax-weight precompute).
// ---------------------------------------------------------------------------
__global__ void hist_kernel(const int* __restrict__ dst, int* __restrict__ deg) {
  const int i = blockIdx.x * blockDim.x + threadIdx.x;
  if (i < EE) atomicAdd(&deg[dst[i]], 1);
}

__global__ __launch_bounds__(256) void alloc_kernel(const int* __restrict__ deg,
                                                    int* __restrict__ rowptr,
                                                    int* __restrict__ cur,
                                                    int* __restrict__ counter) {
  const int i = blockIdx.x * blockDim.x + threadIdx.x;
  const int lane = threadIdx.x & 63;
  const int d = (i < NN) ? deg[i] : 0;
  int s = d;
#pragma unroll
  for (int off = 1; off < 64; off <<= 1) {
    const int v = __shfl_up(s, off, 64);
    if (lane >= off) s += v;
  }
  const int total = __shfl(s, 63, 64);
  int base = 0;
  if (lane == 63) base = atomicAdd(counter, total);
  base = __shfl(base, 63, 64);
  const int p = base + s - d;
  if (i < NN) {
    rowptr[i] = p;
    cur[i] = p;
  }
}

__global__ void scatter_kernel(const int* __restrict__ src,
                               const int* __restrict__ dst,
                               const float* __restrict__ a_s,
                               const float* __restrict__ a_d,
                               int* __restrict__ cur, int* __restrict__ col,
                               float4* __restrict__ wbuf) {
  const int i = blockIdx.x * blockDim.x + threadIdx.x;
  if (i >= EE) return;
  const int s = src[i];
  const int d = dst[i];
  const int p = atomicAdd(&cur[d], 1);
  col[p] = s;
  const float4 as = *(const float4*)&a_s[s * 4];
  const float4 ad = *(const float4*)&a_d[d * 4];
  float4 l;
  l.x = as.x + ad.x;
  l.y = as.y + ad.y;
  l.z = as.z + ad.z;
  l.w = as.w + ad.w;
  l.x = l.x > 0.f ? l.x : NEG_SLOPE * l.x;
  l.y = l.y > 0.f ? l.y : NEG_SLOPE * l.y;
  l.z = l.z > 0.f ? l.z : NEG_SLOPE * l.z;
  l.w = l.w > 0.f ? l.w : NEG_SLOPE * l.w;
  float4 e;
  e.x = __expf(l.x);
  e.y = __expf(l.y);
  e.z = __expf(l.z);
  e.w = __expf(l.w);
  wbuf[p] = e;
}

// ---------------------------------------------------------------------------
// Aggregate: one wave per destination node. Gathers bf16 features, sequential
// precomputed edge weights; normalize once; +bias, relu.
// ---------------------------------------------------------------------------
__global__ __launch_bounds__(256) void aggregate_kernel(
    const unsigned short* __restrict__ hb, const float* __restrict__ a_s,
    const float* __restrict__ a_d, const float* __restrict__ bias_gat,
    const int* __restrict__ rowptr, const int* __restrict__ deg,
    const int* __restrict__ col, const float4* __restrict__ wbuf,
    float* __restrict__ out1) {
  const int wave = (blockIdx.x * blockDim.x + threadIdx.x) >> 6;
  const int lane = threadIdx.x & 63;
  if (wave >= NN) return;
  const int n = wave;
  const bool sel = lane >= 32;  // head pair select: (0,2) vs (1,3)

  float acc0, acc1, ds0, ds1;
  {  // self loop
    const float4 as = *(const float4*)&a_s[n * 4];
    const float4 ad = *(const float4*)&a_d[n * 4];
    float4 l;
    l.x = as.x + ad.x;
    l.y = as.y + ad.y;
    l.z = as.z + ad.z;
    l.w = as.w + ad.w;
    l.x = l.x > 0.f ? l.x : NEG_SLOPE * l.x;
    l.y = l.y > 0.f ? l.y : NEG_SLOPE * l.y;
    l.z = l.z > 0.f ? l.z : NEG_SLOPE * l.z;
    l.w = l.w > 0.f ? l.w : NEG_SLOPE * l.w;
    const float e0 = __expf(sel ? l.y : l.x);
    const float e1 = __expf(sel ? l.w : l.z);
    acc0 = e0 * bf2f(hb[(size_t)n * 128 + lane]);
    acc1 = e1 * bf2f(hb[(size_t)n * 128 + 64 + lane]);
    ds0 = e0;
    ds1 = e1;
  }
  const int beg = rowptr[n];
  const int end = beg + deg[n];
  int i = beg;
  for (; i + 2 <= end; i += 2) {
    const int s0 = col[i];
    const int s1 = col[i + 1];
    const float4 w0 = wbuf[i];
    const float4 w1 = wbuf[i + 1];
    const unsigned short g00 = hb[(size_t)s0 * 128 + lane];
    const unsigned short g01 = hb[(size_t)s0 * 128 + 64 + lane];
    const unsigned short g10 = hb[(size_t)s1 * 128 + lane];
    const unsigned short g11 = hb[(size_t)s1 * 128 + 64 + lane];
    const float c00 = sel ? w0.y : w0.x;
    const float c01 = sel ? w0.w : w0.z;
    const float c10 = sel ? w1.y : w1.x;
    const float c11 = sel ? w1.w : w1.z;
    acc0 = fmaf(c00, bf2f(g00), acc0);
    acc1 = fmaf(c01, bf2f(g01), acc1);
    acc0 = fmaf(c10, bf2f(g10), acc0);
    acc1 = fmaf(c11, bf2f(g11), acc1);
    ds0 += c00 + c10;
    ds1 += c01 + c11;
  }
  if (i < end) {
    const int s0 = col[i];
    const float4 w0 = wbuf[i];
    const float c00 = sel ? w0.y : w0.x;
    const float c01 = sel ? w0.w : w0.z;
    acc0 = fmaf(c00, bf2f(hb[(size_t)s0 * 128 + lane]), acc0);
    acc1 = fmaf(c01, bf2f(hb[(size_t)s0 * 128 + 64 + lane]), acc1);
    ds0 += c00;
    ds1 += c01;
  }
  float v0 = acc0 / ds0 + bias_gat[lane];
  float v1 = acc1 / ds1 + bias_gat[64 + lane];
  out1[(size_t)n * 128 + lane] = v0 > 0.f ? v0 : 0.f;
  out1[(size_t)n * 128 + 64 + lane] = v1 > 0.f ? v1 : 0.f;
}

// ---------------------------------------------------------------------------
extern "C" void kernel_launch(void* const* d_in, const int* in_sizes, int n_in,
                              void* d_out, int out_size, void* d_ws,
                              size_t ws_size, hipStream_t stream) {
  const float* x = (const float*)d_in[0];
  const int* ei = (const int*)d_in[1];  // [2,E]: row0=src, row1=dst
  const float* W_gat = (const float*)d_in[2];
  const float* att_src = (const float*)d_in[3];
  const float* att_dst = (const float*)d_in[4];
  const float* bias_gat = (const float*)d_in[5];
  const float* W_lin = (const float*)d_in[6];
  const float* b_lin = (const float*)d_in[7];
  float* out = (float*)d_out;

  // workspace carve-up (16B aligned). wbuf aliases h (dead after attn_dots).
  char* ws = (char*)d_ws;
  size_t off = 0;
  float* h = (float*)(ws + off); off += (size_t)NN * 128 * 4;        // 51.2 MB
  float* a_s = (float*)(ws + off); off += (size_t)NN * 4 * 4;
  float* a_d = (float*)(ws + off); off += (size_t)NN * 4 * 4;
  float* out1 = (float*)(ws + off); off += (size_t)NN * 128 * 4;     // 51.2 MB
  int* deg = (int*)(ws + off); off += (size_t)NN * 4;
  int* rowptr = (int*)(ws + off); off += (size_t)(NN + 4) * 4;
  int* cur = (int*)(ws + off); off += (size_t)NN * 4;
  int* counter = (int*)(ws + off); off += 16;
  int* col = (int*)(ws + off); off += (size_t)EE * 4;                // 6.4 MB
  unsigned short* hb = (unsigned short*)(ws + off);
  off += (size_t)NN * 128 * 2;                                       // 25.6 MB
  float4* wbuf = (float4*)h;  // alias: EE*16 = 25.6 MB < 51.2 MB

  const int* src = ei;
  const int* dst = ei + EE;

  // 1) h = x @ W_gat^T
  gemm128<<<(NN + 63) / 64, 256, 0, stream>>>(x, W_gat, nullptr, h, NN);
  // 2) attention dots + bf16 feature copy
  attn_dots<<<(NN * NHEAD + 255) / 256, 256, 0, stream>>>(h, att_src, att_dst,
                                                          a_s, a_d, hb);
  // 3) CSR by destination + fused edge-weight precompute
  hipMemsetAsync(deg, 0, (size_t)NN * 4, stream);
  hipMemsetAsync(counter, 0, 16, stream);
  hist_kernel<<<(EE + 255) / 256, 256, 0, stream>>>(dst, deg);
  alloc_kernel<<<(NN + 255) / 256, 256, 0, stream>>>(deg, rowptr, cur, counter);
  scatter_kernel<<<(EE + 255) / 256, 256, 0, stream>>>(src, dst, a_s, a_d, cur,
                                                       col, wbuf);
  // 4) softmax-weighted aggregation (+bias, relu) — one wave per node
  aggregate_kernel<<<(NN + 3) / 4, 256, 0, stream>>>(hb, a_s, a_d, bias_gat,
                                                     rowptr, deg, col, wbuf,
                                                     out1);
  // 5) out = out1 @ W_lin^T + b_lin
  gemm128<<<(NN + 63) / 64, 256, 0, stream>>>(out1, W_lin, b_lin, out, NN);
}

// Round 4
// 477.575 us; speedup vs baseline: 1.7065x; 1.1501x over previous
//
#include <hip/hip_runtime.h>
#include <hip/hip_bf16.h>

// Problem constants (match reference)
#define NN 100000
#define EE 1600000
#define INF_DIM 128
#define NHEAD 4
#define HDIM 32
#define NEG_SLOPE 0.2f

typedef __attribute__((ext_vector_type(8))) short short8;
typedef __attribute__((ext_vector_type(4))) float floatx4;

__device__ __forceinline__ unsigned short f2bf(float x) {
  union { float f; unsigned int u; } c;
  c.f = x;
  const unsigned int r = c.u + 0x7fffu + ((c.u >> 16) & 1u);  // RNE
  return (unsigned short)(r >> 16);
}
__device__ __forceinline__ float bf2f(unsigned short u) {
  union { unsigned int u; float f; } c;
  c.u = ((unsigned int)u) << 16;
  return c.f;
}
// unpack packed pair of bf16 (from one u32) to two floats
__device__ __forceinline__ void bf2x(unsigned int u, float& lo, float& hi) {
  union { unsigned int u; float f; } a, b;
  a.u = u << 16;
  b.u = u & 0xffff0000u;
  lo = a.f;
  hi = b.f;
}

// ---------------------------------------------------------------------------
// MFMA GEMM: C[M,128] = A[M,128] @ W[128,128]^T (+bias), W row-major [o][k].
// A input: fp32 (Af) or bf16 (Ab). Output: bf16 (Cb) or fp32+bias (Cf).
// Block = 64 rows x 128 cols, 4 waves; K=128 staged once to LDS (bf16).
// LDS rows padded to 136 shorts (272 B) -> ds_read_b128 is 2-way (free).
// ---------------------------------------------------------------------------
#define LDA 136

__global__ __launch_bounds__(256) void gemm_mfma(
    const float* __restrict__ Af, const unsigned short* __restrict__ Ab,
    const float* __restrict__ W, const float* __restrict__ bias,
    unsigned short* __restrict__ Cb, float* __restrict__ Cf, int M) {
  __shared__ unsigned short sA[64 * LDA];   // [m][k]
  __shared__ unsigned short sW[128 * LDA];  // [o][k] == B^T
  const int tid = threadIdx.x;
  const int m0 = blockIdx.x * 64;

  // stage W (fp32 -> bf16): thread t covers row t>>1, cols (t&1)*64..+63
  {
    const int r = tid >> 1;
    const int c0 = (tid & 1) * 64;
#pragma unroll
    for (int j = 0; j < 16; ++j) {
      const float4 v = *(const float4*)&W[r * 128 + c0 + j * 4];
      ushort4 u;
      u.x = f2bf(v.x);
      u.y = f2bf(v.y);
      u.z = f2bf(v.z);
      u.w = f2bf(v.w);
      *(ushort4*)&sW[r * LDA + c0 + j * 4] = u;
    }
  }
  // stage A: thread t covers row t>>2, cols (t&3)*32..+31
  {
    const int r = tid >> 2;
    const int gm = m0 + r;
    const int c0 = (tid & 3) * 32;
    if (gm < M) {
      if (Af) {
#pragma unroll
        for (int j = 0; j < 8; ++j) {
          const float4 v = *(const float4*)&Af[(size_t)gm * 128 + c0 + j * 4];
          ushort4 u;
          u.x = f2bf(v.x);
          u.y = f2bf(v.y);
          u.z = f2bf(v.z);
          u.w = f2bf(v.w);
          *(ushort4*)&sA[r * LDA + c0 + j * 4] = u;
        }
      } else {
#pragma unroll
        for (int j = 0; j < 4; ++j) {
          const uint4 v = *(const uint4*)&Ab[(size_t)gm * 128 + c0 + j * 8];
          *(uint4*)&sA[r * LDA + c0 + j * 8] = v;
        }
      }
    } else {
#pragma unroll
      for (int j = 0; j < 4; ++j) {
        uint4 z;
        z.x = z.y = z.z = z.w = 0u;
        *(uint4*)&sA[r * LDA + c0 + j * 8] = z;
      }
    }
  }
  __syncthreads();

  const int wv = tid >> 6;  // wave 0..3 -> m-subtile
  const int lane = tid & 63;
  const int l16 = lane & 15;
  const int quad = lane >> 4;

  floatx4 acc[8];
#pragma unroll
  for (int i = 0; i < 8; ++i) acc[i] = (floatx4){0.f, 0.f, 0.f, 0.f};

  const unsigned short* aRow = &sA[(wv * 16 + l16) * LDA + quad * 8];
#pragma unroll
  for (int kc = 0; kc < 4; ++kc) {
    const short8 afrag = *(const short8*)(aRow + kc * 32);
#pragma unroll
    for (int nt = 0; nt < 8; ++nt) {
      const short8 bfrag =
          *(const short8*)&sW[(nt * 16 + l16) * LDA + kc * 32 + quad * 8];
      acc[nt] =
          __builtin_amdgcn_mfma_f32_16x16x32_bf16(afrag, bfrag, acc[nt], 0, 0, 0);
    }
  }

  // epilogue: C/D layout col=lane&15, row=quad*4+reg
  const int mrow = m0 + wv * 16 + quad * 4;
#pragma unroll
  for (int nt = 0; nt < 8; ++nt) {
    const int col = nt * 16 + l16;
    const float bv = Cf ? bias[col] : 0.f;
#pragma unroll
    for (int r = 0; r < 4; ++r) {
      const int gm = mrow + r;
      if (gm < M) {
        const float v = acc[nt][r];
        if (Cb)
          Cb[(size_t)gm * 128 + col] = f2bf(v);
        else
          Cf[(size_t)gm * 128 + col] = v + bv;
      }
    }
  }
}

// ---------------------------------------------------------------------------
// a_s[n,h] = dot(hb[n,h,:], att_src[h,:]); a_d likewise. One thread per (n,h).
// ---------------------------------------------------------------------------
__global__ void attn_dots(const unsigned short* __restrict__ hb,
                          const float* __restrict__ att_src,
                          const float* __restrict__ att_dst,
                          float* __restrict__ a_s, float* __restrict__ a_d) {
  const int idx = blockIdx.x * blockDim.x + threadIdx.x;  // n*4 + head
  if (idx >= NN * NHEAD) return;
  const int hd = idx & 3;
  const uint4* hp = (const uint4*)(hb + (size_t)idx * HDIM);
  const float4* as = (const float4*)(att_src + hd * HDIM);
  const float4* ad = (const float4*)(att_dst + hd * HDIM);
  float s = 0.f, d = 0.f;
#pragma unroll
  for (int q = 0; q < 4; ++q) {
    const uint4 u = hp[q];
    float v[8];
    bf2x(u.x, v[0], v[1]);
    bf2x(u.y, v[2], v[3]);
    bf2x(u.z, v[4], v[5]);
    bf2x(u.w, v[6], v[7]);
    const float4 a0 = as[q * 2], a1 = as[q * 2 + 1];
    const float4 b0 = ad[q * 2], b1 = ad[q * 2 + 1];
    s += v[0] * a0.x + v[1] * a0.y + v[2] * a0.z + v[3] * a0.w;
    s += v[4] * a1.x + v[5] * a1.y + v[6] * a1.z + v[7] * a1.w;
    d += v[0] * b0.x + v[1] * b0.y + v[2] * b0.z + v[3] * b0.w;
    d += v[4] * b1.x + v[5] * b1.y + v[6] * b1.z + v[7] * b1.w;
  }
  a_s[idx] = s;
  a_d[idx] = d;
}

// ---------------------------------------------------------------------------
// CSR build: histogram of dst, segment allocation via wave-scan + one atomic
// per wave, scatter (fused with per-edge softmax-weight precompute).
// ---------------------------------------------------------------------------
__global__ void hist_kernel(const int* __restrict__ dst, int* __restrict__ deg) {
  const int i = blockIdx.x * blockDim.x + threadIdx.x;
  if (i < EE) atomicAdd(&deg[dst[i]], 1);
}

__global__ __launch_bounds__(256) void alloc_kernel(const int* __restrict__ deg,
                                                    int* __restrict__ rowptr,
                                                    int* __restrict__ cur,
                                                    int* __restrict__ counter) {
  const int i = blockIdx.x * blockDim.x + threadIdx.x;
  const int lane = threadIdx.x & 63;
  const int d = (i < NN) ? deg[i] : 0;
  int s = d;
#pragma unroll
  for (int off = 1; off < 64; off <<= 1) {
    const int v = __shfl_up(s, off, 64);
    if (lane >= off) s += v;
  }
  const int total = __shfl(s, 63, 64);
  int base = 0;
  if (lane == 63) base = atomicAdd(counter, total);
  base = __shfl(base, 63, 64);
  const int p = base + s - d;
  if (i < NN) {
    rowptr[i] = p;
    cur[i] = p;
  }
}

__global__ void scatter_kernel(const int* __restrict__ src,
                               const int* __restrict__ dst,
                               const float* __restrict__ a_s,
                               const float* __restrict__ a_d,
                               int* __restrict__ cur, int* __restrict__ col,
                               float4* __restrict__ wbuf) {
  const int i = blockIdx.x * blockDim.x + threadIdx.x;
  if (i >= EE) return;
  const int s = src[i];
  const int d = dst[i];
  const int p = atomicAdd(&cur[d], 1);
  col[p] = s;
  const float4 as = *(const float4*)&a_s[s * 4];
  const float4 ad = *(const float4*)&a_d[d * 4];
  float4 l;
  l.x = as.x + ad.x;
  l.y = as.y + ad.y;
  l.z = as.z + ad.z;
  l.w = as.w + ad.w;
  l.x = l.x > 0.f ? l.x : NEG_SLOPE * l.x;
  l.y = l.y > 0.f ? l.y : NEG_SLOPE * l.y;
  l.z = l.z > 0.f ? l.z : NEG_SLOPE * l.z;
  l.w = l.w > 0.f ? l.w : NEG_SLOPE * l.w;
  float4 e;
  e.x = __expf(l.x);
  e.y = __expf(l.y);
  e.z = __expf(l.z);
  e.w = __expf(l.w);
  wbuf[p] = e;
}

// ---------------------------------------------------------------------------
// Aggregate: one wave per destination node. Gathers bf16 features, sequential
// precomputed edge weights; normalize once; +bias, relu; bf16 output.
// ---------------------------------------------------------------------------
__global__ __launch_bounds__(256) void aggregate_kernel(
    const unsigned short* __restrict__ hb, const float* __restrict__ a_s,
    const float* __restrict__ a_d, const float* __restrict__ bias_gat,
    const int* __restrict__ rowptr, const int* __restrict__ deg,
    const int* __restrict__ col, const float4* __restrict__ wbuf,
    unsigned short* __restrict__ ob) {
  const int wave = (blockIdx.x * blockDim.x + threadIdx.x) >> 6;
  const int lane = threadIdx.x & 63;
  if (wave >= NN) return;
  const int n = wave;
  const bool sel = lane >= 32;  // head pair select: (0,2) vs (1,3)

  float acc0, acc1, ds0, ds1;
  {  // self loop
    const float4 as = *(const float4*)&a_s[n * 4];
    const float4 ad = *(const float4*)&a_d[n * 4];
    float4 l;
    l.x = as.x + ad.x;
    l.y = as.y + ad.y;
    l.z = as.z + ad.z;
    l.w = as.w + ad.w;
    l.x = l.x > 0.f ? l.x : NEG_SLOPE * l.x;
    l.y = l.y > 0.f ? l.y : NEG_SLOPE * l.y;
    l.z = l.z > 0.f ? l.z : NEG_SLOPE * l.z;
    l.w = l.w > 0.f ? l.w : NEG_SLOPE * l.w;
    const float e0 = __expf(sel ? l.y : l.x);
    const float e1 = __expf(sel ? l.w : l.z);
    acc0 = e0 * bf2f(hb[(size_t)n * 128 + lane]);
    acc1 = e1 * bf2f(hb[(size_t)n * 128 + 64 + lane]);
    ds0 = e0;
    ds1 = e1;
  }
  const int beg = rowptr[n];
  const int end = beg + deg[n];
  int i = beg;
  for (; i + 2 <= end; i += 2) {
    const int s0 = col[i];
    const int s1 = col[i + 1];
    const float4 w0 = wbuf[i];
    const float4 w1 = wbuf[i + 1];
    const unsigned short g00 = hb[(size_t)s0 * 128 + lane];
    const unsigned short g01 = hb[(size_t)s0 * 128 + 64 + lane];
    const unsigned short g10 = hb[(size_t)s1 * 128 + lane];
    const unsigned short g11 = hb[(size_t)s1 * 128 + 64 + lane];
    const float c00 = sel ? w0.y : w0.x;
    const float c01 = sel ? w0.w : w0.z;
    const float c10 = sel ? w1.y : w1.x;
    const float c11 = sel ? w1.w : w1.z;
    acc0 = fmaf(c00, bf2f(g00), acc0);
    acc1 = fmaf(c01, bf2f(g01), acc1);
    acc0 = fmaf(c10, bf2f(g10), acc0);
    acc1 = fmaf(c11, bf2f(g11), acc1);
    ds0 += c00 + c10;
    ds1 += c01 + c11;
  }
  if (i < end) {
    const int s0 = col[i];
    const float4 w0 = wbuf[i];
    const float c00 = sel ? w0.y : w0.x;
    const float c01 = sel ? w0.w : w0.z;
    acc0 = fmaf(c00, bf2f(hb[(size_t)s0 * 128 + lane]), acc0);
    acc1 = fmaf(c01, bf2f(hb[(size_t)s0 * 128 + 64 + lane]), acc1);
    ds0 += c00;
    ds1 += c01;
  }
  const float v0 = acc0 / ds0 + bias_gat[lane];
  const float v1 = acc1 / ds1 + bias_gat[64 + lane];
  ob[(size_t)n * 128 + lane] = f2bf(v0 > 0.f ? v0 : 0.f);
  ob[(size_t)n * 128 + 64 + lane] = f2bf(v1 > 0.f ? v1 : 0.f);
}

// ---------------------------------------------------------------------------
extern "C" void kernel_launch(void* const* d_in, const int* in_sizes, int n_in,
                              void* d_out, int out_size, void* d_ws,
                              size_t ws_size, hipStream_t stream) {
  const float* x = (const float*)d_in[0];
  const int* ei = (const int*)d_in[1];  // [2,E]: row0=src, row1=dst
  const float* W_gat = (const float*)d_in[2];
  const float* att_src = (const float*)d_in[3];
  const float* att_dst = (const float*)d_in[4];
  const float* bias_gat = (const float*)d_in[5];
  const float* W_lin = (const float*)d_in[6];
  const float* b_lin = (const float*)d_in[7];
  float* out = (float*)d_out;

  // workspace carve-up (16B aligned)
  char* ws = (char*)d_ws;
  size_t off = 0;
  unsigned short* hb = (unsigned short*)(ws + off);
  off += (size_t)NN * 128 * 2;  // 25.6 MB
  unsigned short* ob = (unsigned short*)(ws + off);
  off += (size_t)NN * 128 * 2;  // 25.6 MB
  float* a_s = (float*)(ws + off); off += (size_t)NN * 4 * 4;
  float* a_d = (float*)(ws + off); off += (size_t)NN * 4 * 4;
  int* deg = (int*)(ws + off); off += (size_t)NN * 4;
  int* rowptr = (int*)(ws + off); off += (size_t)(NN + 4) * 4;
  int* cur = (int*)(ws + off); off += (size_t)NN * 4;
  int* counter = (int*)(ws + off); off += 16;
  int* col = (int*)(ws + off); off += (size_t)EE * 4;  // 6.4 MB
  float4* wbuf = (float4*)(ws + off); off += (size_t)EE * 16;  // 25.6 MB

  const int* src = ei;
  const int* dst = ei + EE;

  // 1) hb = bf16(x @ W_gat^T)  [MFMA]
  gemm_mfma<<<(NN + 63) / 64, 256, 0, stream>>>(x, nullptr, W_gat, nullptr, hb,
                                                nullptr, NN);
  // 2) attention dots from bf16 features
  attn_dots<<<(NN * NHEAD + 255) / 256, 256, 0, stream>>>(hb, att_src, att_dst,
                                                          a_s, a_d);
  // 3) CSR by destination + fused edge-weight precompute
  hipMemsetAsync(deg, 0, (size_t)NN * 4, stream);
  hipMemsetAsync(counter, 0, 16, stream);
  hist_kernel<<<(EE + 255) / 256, 256, 0, stream>>>(dst, deg);
  alloc_kernel<<<(NN + 255) / 256, 256, 0, stream>>>(deg, rowptr, cur, counter);
  scatter_kernel<<<(EE + 255) / 256, 256, 0, stream>>>(src, dst, a_s, a_d, cur,
                                                       col, wbuf);
  // 4) softmax-weighted aggregation (+bias, relu) -> bf16
  aggregate_kernel<<<(NN + 3) / 4, 256, 0, stream>>>(hb, a_s, a_d, bias_gat,
                                                     rowptr, deg, col, wbuf, ob);
  // 5) out = ob @ W_lin^T + b_lin  [MFMA]
  gemm_mfma<<<(NN + 63) / 64, 256, 0, stream>>>(nullptr, ob, W_lin, b_lin,
                                                nullptr, out, NN);
}

// Round 5
// 444.768 us; speedup vs baseline: 1.8324x; 1.0738x over previous
//
#include <hip/hip_runtime.h>
#include <hip/hip_bf16.h>
#include <hip/hip_fp16.h>

// Problem constants (match reference)
#define NN 100000
#define EE 1600000
#define INF_DIM 128
#define NHEAD 4
#define HDIM 32
#define NEG_SLOPE 0.2f

typedef __attribute__((ext_vector_type(8))) short short8;
typedef __attribute__((ext_vector_type(4))) float floatx4;

__device__ __forceinline__ unsigned short f2bf(float x) {
  union { float f; unsigned int u; } c;
  c.f = x;
  const unsigned int r = c.u + 0x7fffu + ((c.u >> 16) & 1u);  // RNE
  return (unsigned short)(r >> 16);
}
__device__ __forceinline__ float bf2f(unsigned short u) {
  union { unsigned int u; float f; } c;
  c.u = ((unsigned int)u) << 16;
  return c.f;
}
// unpack packed pair of bf16 (from one u32) to two floats
__device__ __forceinline__ void bf2x(unsigned int u, float& lo, float& hi) {
  union { unsigned int u; float f; } a, b;
  a.u = u << 16;
  b.u = u & 0xffff0000u;
  lo = a.f;
  hi = b.f;
}
__device__ __forceinline__ unsigned int packh2(float a, float b) {
  const __half ha = __float2half(a), hb = __float2half(b);
  const unsigned short ua = *(const unsigned short*)&ha;
  const unsigned short ub = *(const unsigned short*)&hb;
  return (unsigned int)ua | ((unsigned int)ub << 16);
}
// select fp16 weight for this lane's head out of packed {y=h01, z=h23}
__device__ __forceinline__ float pickw(const int4 e, const int head) {
  const unsigned int d = (head & 2) ? (unsigned int)e.z : (unsigned int)e.y;
  const unsigned short us =
      (head & 1) ? (unsigned short)(d >> 16) : (unsigned short)(d & 0xffffu);
  const __half h = *(const __half*)&us;
  return __half2float(h);
}

// ---------------------------------------------------------------------------
// MFMA GEMM: C[M,128] = A[M,128] @ W[128,128]^T (+bias), W row-major [o][k].
// A input: fp32 (Af) or bf16 (Ab). Output: bf16 (Cb) or fp32+bias (Cf).
// Block = 64 rows x 128 cols, 4 waves; K=128 staged once to LDS (bf16).
// ---------------------------------------------------------------------------
#define LDA 136

__global__ __launch_bounds__(256) void gemm_mfma(
    const float* __restrict__ Af, const unsigned short* __restrict__ Ab,
    const float* __restrict__ W, const float* __restrict__ bias,
    unsigned short* __restrict__ Cb, float* __restrict__ Cf, int M) {
  __shared__ unsigned short sA[64 * LDA];   // [m][k]
  __shared__ unsigned short sW[128 * LDA];  // [o][k] == B^T
  const int tid = threadIdx.x;
  const int m0 = blockIdx.x * 64;

  {
    const int r = tid >> 1;
    const int c0 = (tid & 1) * 64;
#pragma unroll
    for (int j = 0; j < 16; ++j) {
      const float4 v = *(const float4*)&W[r * 128 + c0 + j * 4];
      ushort4 u;
      u.x = f2bf(v.x);
      u.y = f2bf(v.y);
      u.z = f2bf(v.z);
      u.w = f2bf(v.w);
      *(ushort4*)&sW[r * LDA + c0 + j * 4] = u;
    }
  }
  {
    const int r = tid >> 2;
    const int gm = m0 + r;
    const int c0 = (tid & 3) * 32;
    if (gm < M) {
      if (Af) {
#pragma unroll
        for (int j = 0; j < 8; ++j) {
          const float4 v = *(const float4*)&Af[(size_t)gm * 128 + c0 + j * 4];
          ushort4 u;
          u.x = f2bf(v.x);
          u.y = f2bf(v.y);
          u.z = f2bf(v.z);
          u.w = f2bf(v.w);
          *(ushort4*)&sA[r * LDA + c0 + j * 4] = u;
        }
      } else {
#pragma unroll
        for (int j = 0; j < 4; ++j) {
          const uint4 v = *(const uint4*)&Ab[(size_t)gm * 128 + c0 + j * 8];
          *(uint4*)&sA[r * LDA + c0 + j * 8] = v;
        }
      }
    } else {
#pragma unroll
      for (int j = 0; j < 4; ++j) {
        uint4 z;
        z.x = z.y = z.z = z.w = 0u;
        *(uint4*)&sA[r * LDA + c0 + j * 8] = z;
      }
    }
  }
  __syncthreads();

  const int wv = tid >> 6;
  const int lane = tid & 63;
  const int l16 = lane & 15;
  const int quad = lane >> 4;

  floatx4 acc[8];
#pragma unroll
  for (int i = 0; i < 8; ++i) acc[i] = (floatx4){0.f, 0.f, 0.f, 0.f};

  const unsigned short* aRow = &sA[(wv * 16 + l16) * LDA + quad * 8];
#pragma unroll
  for (int kc = 0; kc < 4; ++kc) {
    const short8 afrag = *(const short8*)(aRow + kc * 32);
#pragma unroll
    for (int nt = 0; nt < 8; ++nt) {
      const short8 bfrag =
          *(const short8*)&sW[(nt * 16 + l16) * LDA + kc * 32 + quad * 8];
      acc[nt] =
          __builtin_amdgcn_mfma_f32_16x16x32_bf16(afrag, bfrag, acc[nt], 0, 0, 0);
    }
  }

  const int mrow = m0 + wv * 16 + quad * 4;
#pragma unroll
  for (int nt = 0; nt < 8; ++nt) {
    const int col = nt * 16 + l16;
    const float bv = Cf ? bias[col] : 0.f;
#pragma unroll
    for (int r = 0; r < 4; ++r) {
      const int gm = mrow + r;
      if (gm < M) {
        const float v = acc[nt][r];
        if (Cb)
          Cb[(size_t)gm * 128 + col] = f2bf(v);
        else
          Cf[(size_t)gm * 128 + col] = v + bv;
      }
    }
  }
}

// ---------------------------------------------------------------------------
// a_s[n,h] = dot(hb[n,h,:], att_src[h,:]); a_d likewise. One thread per (n,h).
// ---------------------------------------------------------------------------
__global__ void attn_dots(const unsigned short* __restrict__ hb,
                          const float* __restrict__ att_src,
                          const float* __restrict__ att_dst,
                          float* __restrict__ a_s, float* __restrict__ a_d) {
  const int idx = blockIdx.x * blockDim.x + threadIdx.x;  // n*4 + head
  if (idx >= NN * NHEAD) return;
  const int hd = idx & 3;
  const uint4* hp = (const uint4*)(hb + (size_t)idx * HDIM);
  const float4* as = (const float4*)(att_src + hd * HDIM);
  const float4* ad = (const float4*)(att_dst + hd * HDIM);
  float s = 0.f, d = 0.f;
#pragma unroll
  for (int q = 0; q < 4; ++q) {
    const uint4 u = hp[q];
    float v[8];
    bf2x(u.x, v[0], v[1]);
    bf2x(u.y, v[2], v[3]);
    bf2x(u.z, v[4], v[5]);
    bf2x(u.w, v[6], v[7]);
    const float4 a0 = as[q * 2], a1 = as[q * 2 + 1];
    const float4 b0 = ad[q * 2], b1 = ad[q * 2 + 1];
    s += v[0] * a0.x + v[1] * a0.y + v[2] * a0.z + v[3] * a0.w;
    s += v[4] * a1.x + v[5] * a1.y + v[6] * a1.z + v[7] * a1.w;
    d += v[0] * b0.x + v[1] * b0.y + v[2] * b0.z + v[3] * b0.w;
    d += v[4] * b1.x + v[5] * b1.y + v[6] * b1.z + v[7] * b1.w;
  }
  a_s[idx] = s;
  a_d[idx] = d;
}

// ---------------------------------------------------------------------------
// CSR build: histogram of dst, segment allocation via wave-scan + one atomic
// per wave, scatter (fused with per-edge softmax-weight precompute; emits
// 16 B records {src, fp16 w01, fp16 w23, 0}).
// ---------------------------------------------------------------------------
__global__ void hist_kernel(const int* __restrict__ dst, int* __restrict__ deg) {
  const int i = blockIdx.x * blockDim.x + threadIdx.x;
  if (i < EE) atomicAdd(&deg[dst[i]], 1);
}

__global__ __launch_bounds__(256) void alloc_kernel(const int* __restrict__ deg,
                                                    int* __restrict__ rowptr,
                                                    int* __restrict__ cur,
                                                    int* __restrict__ counter) {
  const int i = blockIdx.x * blockDim.x + threadIdx.x;
  const int lane = threadIdx.x & 63;
  const int d = (i < NN) ? deg[i] : 0;
  int s = d;
#pragma unroll
  for (int off = 1; off < 64; off <<= 1) {
    const int v = __shfl_up(s, off, 64);
    if (lane >= off) s += v;
  }
  const int total = __shfl(s, 63, 64);
  int base = 0;
  if (lane == 63) base = atomicAdd(counter, total);
  base = __shfl(base, 63, 64);
  const int p = base + s - d;
  if (i < NN) {
    rowptr[i] = p;
    cur[i] = p;
  }
}

__global__ void scatter_kernel(const int* __restrict__ src,
                               const int* __restrict__ dst,
                               const float* __restrict__ a_s,
                               const float* __restrict__ a_d,
                               int* __restrict__ cur, int4* __restrict__ ebuf) {
  const int i = blockIdx.x * blockDim.x + threadIdx.x;
  if (i >= EE) return;
  const int s = src[i];
  const int d = dst[i];
  const int p = atomicAdd(&cur[d], 1);
  const float4 as = *(const float4*)&a_s[s * 4];
  const float4 ad = *(const float4*)&a_d[d * 4];
  float4 l;
  l.x = as.x + ad.x;
  l.y = as.y + ad.y;
  l.z = as.z + ad.z;
  l.w = as.w + ad.w;
  l.x = l.x > 0.f ? l.x : NEG_SLOPE * l.x;
  l.y = l.y > 0.f ? l.y : NEG_SLOPE * l.y;
  l.z = l.z > 0.f ? l.z : NEG_SLOPE * l.z;
  l.w = l.w > 0.f ? l.w : NEG_SLOPE * l.w;
  int4 e;
  e.x = s;
  e.y = (int)packh2(__expf(l.x), __expf(l.y));
  e.z = (int)packh2(__expf(l.z), __expf(l.w));
  e.w = 0;
  ebuf[p] = e;
}

// ---------------------------------------------------------------------------
// Aggregate: one wave per destination node. Lane l handles features 2l,2l+1
// (both in head l>>4): per edge, ONE broadcast 16B record + ONE dword gather.
// Normalize once; +bias, relu; bf16 packed output.
// ---------------------------------------------------------------------------
__global__ __launch_bounds__(256) void aggregate_kernel(
    const unsigned int* __restrict__ hbd, const float* __restrict__ a_s,
    const float* __restrict__ a_d, const float* __restrict__ bias_gat,
    const int* __restrict__ rowptr, const int* __restrict__ deg,
    const int4* __restrict__ ebuf, unsigned int* __restrict__ obd) {
  const int wave = (blockIdx.x * blockDim.x + threadIdx.x) >> 6;
  const int lane = threadIdx.x & 63;
  if (wave >= NN) return;
  const int n = wave;
  const int head = lane >> 4;

  float acc0, acc1, ds;
  {  // self loop
    float l = a_s[n * 4 + head] + a_d[n * 4 + head];
    l = l > 0.f ? l : NEG_SLOPE * l;
    const float c = __expf(l);
    float f0, f1;
    bf2x(hbd[(size_t)n * 64 + lane], f0, f1);
    acc0 = c * f0;
    acc1 = c * f1;
    ds = c;
  }
  const int beg = rowptr[n];
  const int end = beg + deg[n];
  int i = beg;
  for (; i + 2 <= end; i += 2) {
    const int4 e0 = ebuf[i];
    const int4 e1 = ebuf[i + 1];
    const unsigned int g0 = hbd[(size_t)e0.x * 64 + lane];
    const unsigned int g1 = hbd[(size_t)e1.x * 64 + lane];
    const float c0 = pickw(e0, head);
    const float c1 = pickw(e1, head);
    float f0, f1;
    bf2x(g0, f0, f1);
    acc0 = fmaf(c0, f0, acc0);
    acc1 = fmaf(c0, f1, acc1);
    bf2x(g1, f0, f1);
    acc0 = fmaf(c1, f0, acc0);
    acc1 = fmaf(c1, f1, acc1);
    ds += c0 + c1;
  }
  if (i < end) {
    const int4 e0 = ebuf[i];
    const unsigned int g0 = hbd[(size_t)e0.x * 64 + lane];
    const float c0 = pickw(e0, head);
    float f0, f1;
    bf2x(g0, f0, f1);
    acc0 = fmaf(c0, f0, acc0);
    acc1 = fmaf(c0, f1, acc1);
    ds += c0;
  }
  const float inv = 1.0f / ds;
  const float2 b = *(const float2*)&bias_gat[2 * lane];
  const float v0 = acc0 * inv + b.x;
  const float v1 = acc1 * inv + b.y;
  const unsigned int r0 = f2bf(v0 > 0.f ? v0 : 0.f);
  const unsigned int r1 = f2bf(v1 > 0.f ? v1 : 0.f);
  obd[(size_t)n * 64 + lane] = r0 | (r1 << 16);
}

// ---------------------------------------------------------------------------
extern "C" void kernel_launch(void* const* d_in, const int* in_sizes, int n_in,
                              void* d_out, int out_size, void* d_ws,
                              size_t ws_size, hipStream_t stream) {
  const float* x = (const float*)d_in[0];
  const int* ei = (const int*)d_in[1];  // [2,E]: row0=src, row1=dst
  const float* W_gat = (const float*)d_in[2];
  const float* att_src = (const float*)d_in[3];
  const float* att_dst = (const float*)d_in[4];
  const float* bias_gat = (const float*)d_in[5];
  const float* W_lin = (const float*)d_in[6];
  const float* b_lin = (const float*)d_in[7];
  float* out = (float*)d_out;

  // workspace carve-up (16B aligned)
  char* ws = (char*)d_ws;
  size_t off = 0;
  unsigned short* hb = (unsigned short*)(ws + off);
  off += (size_t)NN * 128 * 2;  // 25.6 MB
  unsigned short* ob = (unsigned short*)(ws + off);
  off += (size_t)NN * 128 * 2;  // 25.6 MB
  float* a_s = (float*)(ws + off); off += (size_t)NN * 4 * 4;
  float* a_d = (float*)(ws + off); off += (size_t)NN * 4 * 4;
  int* deg = (int*)(ws + off); off += (size_t)NN * 4;
  int* rowptr = (int*)(ws + off); off += (size_t)(NN + 4) * 4;
  int* cur = (int*)(ws + off); off += (size_t)NN * 4;
  int* counter = (int*)(ws + off); off += 16;
  int4* ebuf = (int4*)(ws + off); off += (size_t)EE * 16;  // 25.6 MB

  const int* src = ei;
  const int* dst = ei + EE;

  // 1) hb = bf16(x @ W_gat^T)  [MFMA]
  gemm_mfma<<<(NN + 63) / 64, 256, 0, stream>>>(x, nullptr, W_gat, nullptr, hb,
                                                nullptr, NN);
  // 2) attention dots from bf16 features
  attn_dots<<<(NN * NHEAD + 255) / 256, 256, 0, stream>>>(hb, att_src, att_dst,
                                                          a_s, a_d);
  // 3) CSR by destination + fused edge-record precompute
  hipMemsetAsync(deg, 0, (size_t)NN * 4, stream);
  hipMemsetAsync(counter, 0, 16, stream);
  hist_kernel<<<(EE + 255) / 256, 256, 0, stream>>>(dst, deg);
  alloc_kernel<<<(NN + 255) / 256, 256, 0, stream>>>(deg, rowptr, cur, counter);
  scatter_kernel<<<(EE + 255) / 256, 256, 0, stream>>>(src, dst, a_s, a_d, cur,
                                                       ebuf);
  // 4) softmax-weighted aggregation (+bias, relu) -> bf16
  aggregate_kernel<<<(NN + 3) / 4, 256, 0, stream>>>(
      (const unsigned int*)hb, a_s, a_d, bias_gat, rowptr, deg, ebuf,
      (unsigned int*)ob);
  // 5) out = ob @ W_lin^T + b_lin  [MFMA]
  gemm_mfma<<<(NN + 63) / 64, 256, 0, stream>>>(nullptr, ob, W_lin, b_lin,
                                                nullptr, out, NN);
}